// Round 5
// baseline (252.379 us; speedup 1.0000x reference)
//
#include <hip/hip_runtime.h>

// Problem constants
#define T_SEQ 2048
#define C_DIM 1024
#define H_NUM 16
#define H_D   64
#define B_NUM 4
#define M_ROWS 8192   // B*T

typedef __attribute__((ext_vector_type(4))) float f32x4;
typedef __attribute__((ext_vector_type(8))) short bf16x8;   // 8 bf16 = 4 VGPRs (per guide §3)

__device__ __forceinline__ unsigned short f2bf(float f) {
  union { float f; unsigned int u; } a;
  a.f = f;
  unsigned int u = a.u;
  u += 0x7fffu + ((u >> 16) & 1u);   // RNE
  return (unsigned short)(u >> 16);
}

__device__ __forceinline__ unsigned int fbits(float f) {
  union { float f; unsigned int u; } a; a.f = f; return a.u;
}

// pack the high halves (bf16-truncate) of two f32 into one u32: {hi(b), hi(a)}
__device__ __forceinline__ unsigned int pack_hi(float a, float b) {
#if __has_builtin(__builtin_amdgcn_perm)
  return __builtin_amdgcn_perm(fbits(b), fbits(a), 0x07060302u);  // 1 VALU op
#else
  return (fbits(b) & 0xffff0000u) | (fbits(a) >> 16);
#endif
}

// async global->LDS, 16B per lane; LDS dest = wave-uniform base + lane*16
__device__ __forceinline__ void gload_lds16(const unsigned short* g, unsigned short* l) {
  __builtin_amdgcn_global_load_lds(
      (const __attribute__((address_space(1))) unsigned int*)g,
      (__attribute__((address_space(3))) unsigned int*)l, 16, 0, 0);
}

// ---------------------------------------------------------------- fused cast fp32 -> bf16
__global__ __launch_bounds__(256) void cast_all_kernel(const float* __restrict__ x,
                                                       const float* __restrict__ wa,
                                                       const float* __restrict__ wp,
                                                       unsigned short* __restrict__ xb,
                                                       unsigned short* __restrict__ wab,
                                                       unsigned short* __restrict__ wpb) {
  int i = blockIdx.x * 256 + threadIdx.x;
  const float* src;
  unsigned short* dst;
  int off;
  if (i < 2097152) {           // x: 8192*1024/4
    src = x; dst = xb; off = i;
  } else if (i < 2883584) {    // w_attn: 3072*1024/4
    src = wa; dst = wab; off = i - 2097152;
  } else {                     // w_proj: 1024*1024/4
    src = wp; dst = wpb; off = i - 2883584;
  }
  float4 v = reinterpret_cast<const float4*>(src)[off];
  ushort4 o;
  o.x = f2bf(v.x); o.y = f2bf(v.y); o.z = f2bf(v.z); o.w = f2bf(v.w);
  reinterpret_cast<ushort4*>(dst)[off] = o;
}

// ---------------------------------------------------------------- GEMM  C = A * B^T
// Round 5: INTENSITY scaling inside the verified 2-phase structure.
// Closed-form model from rounds 0/3/4 + m97 reference: this structure
// sustains a ~17-23 B/cy/CU staging rate (barrier-drain ceiling; neither
// HBM 9-18% nor L2 ~27% binds), so TF = (BM*BN/(BM+BN)) * rate * 614G.
// Verified: 64*23=912 (m97@4096), 54.9*16.7=563 (round 4). Only lever
// left: tile intensity.
// Change: EPI0 tile 128x96 -> 128x192 (intensity 54.9 -> 76.8, +40%).
//   LDS (128+192)*64*2 = 40KB -> 4 blocks/CU = 160KB exactly.
//   Grid 64x16 = 1024 = EXACTLY one resident round at 4 blocks/CU.
//   acc = 24 x f32x4 = 96 VGPR -- round 2 measured this exact accumulator
//   footprint at 100 VGPRs total, safe under the 128 cap of (256,4).
// Everything else verbatim from the verified structure: BK=64, single LDS
// buffer, pre-swizzled source + linear LDS dest + swizzled reads
// (slot ^ (row&7)), 0 bank conflicts measured every round.
// EPI 0: QKV epilogue -> q*0.125*log2e, k [BH,T,D], v^T [BH,D,T'] k-permuted
// EPI 1: plain fp32 row-major [M,1024] output
template <int EPI>
__global__ __launch_bounds__(256, 4) void gemm_bt_kernel(
    const unsigned short* __restrict__ A,
    const unsigned short* __restrict__ Bw,
    unsigned short* __restrict__ q_ws,
    unsigned short* __restrict__ k_ws,
    unsigned short* __restrict__ v_ws,
    float* __restrict__ outf) {
  constexpr int BN  = (EPI == 0) ? 192 : 64;
  constexpr int NN  = (EPI == 0) ? 3072 : 1024;
  constexpr int NBC = NN / BN;           // 16 or 16
  constexpr int NFR = BN / 32;           // n-frags per wave: 6 or 2
  constexpr int BLD = BN * 8 / 256;      // B staging chunks per thread: 6 or 2
  constexpr int KK  = 1024;
  constexpr int KT  = KK / 64;           // 16
  constexpr int NWG = 64 * NBC;          // 1024 (both; % 8 == 0)

  __shared__ unsigned short lds[8192 + BN * 64];   // A 16KB | B 24KB/8KB

  // T1: bijective XCD-aware swizzle (NWG % 8 == 0)
  const int bid = blockIdx.x;
  const int logical = (bid & 7) * (NWG / 8) + (bid >> 3);
  const int rb = logical / NBC, cb = logical % NBC;

  const int t = threadIdx.x;
  const int w = t >> 6, l = t & 63;
  const int wr = w >> 1, wc = w & 1;
  const int lq = l & 15, lg = l >> 4;

  const size_t a_base = (size_t)(rb * 128) * KK;
  const size_t b_base = (size_t)(cb * BN) * KK;

  // staging chunk c = t + 256*i -> (row=c>>3, slot=c&7), src slot ^= row&7
  int aRow[4], aGs[4];
#pragma unroll
  for (int i = 0; i < 4; ++i) {
    int c = t + 256 * i;
    aRow[i] = c >> 3;
    aGs[i] = (c & 7) ^ (aRow[i] & 7);
  }
  int bRow[BLD], bGs[BLD];
#pragma unroll
  for (int i = 0; i < BLD; ++i) {
    int c = t + 256 * i;
    bRow[i] = c >> 3;
    bGs[i] = (c & 7) ^ (bRow[i] & 7);
  }

  f32x4 acc[4][NFR] = {};

  for (int kt = 0; kt < KT; ++kt) {
    const int ko = kt * 64;
#pragma unroll
    for (int i = 0; i < 4; ++i)
      gload_lds16(A + a_base + (size_t)aRow[i] * KK + ko + aGs[i] * 8,
                  &lds[(t + 256 * i) * 8]);
#pragma unroll
    for (int i = 0; i < BLD; ++i)
      gload_lds16(Bw + b_base + (size_t)bRow[i] * KK + ko + bGs[i] * 8,
                  &lds[8192 + (t + 256 * i) * 8]);
    __syncthreads();   // drains vmcnt -> tile kt fully in LDS

#pragma unroll
    for (int kk = 0; kk < 2; ++kk) {
      const int sg = kk * 4 + lg;
      bf16x8 af[4], bfv[NFR];
#pragma unroll
      for (int i = 0; i < 4; ++i) {
        int R = wr * 64 + i * 16 + lq;
        af[i] = *reinterpret_cast<const bf16x8*>(&lds[(R * 8 + (sg ^ (R & 7))) * 8]);
      }
#pragma unroll
      for (int j = 0; j < NFR; ++j) {
        int R = wc * (BN / 2) + j * 16 + lq;
        bfv[j] = *reinterpret_cast<const bf16x8*>(&lds[8192 + (R * 8 + (sg ^ (R & 7))) * 8]);
      }
#pragma unroll
      for (int i = 0; i < 4; ++i)
#pragma unroll
        for (int j = 0; j < NFR; ++j)
          acc[i][j] = __builtin_amdgcn_mfma_f32_16x16x32_bf16(af[i], bfv[j], acc[i][j], 0, 0, 0);
    }
    __syncthreads();   // all reads of the buffer done before next stage (WAR)
  }

  // epilogue: C/D layout col = lane&15, row = (lane>>4)*4 + reg  (m89-verified)
#pragma unroll
  for (int i = 0; i < 4; ++i) {
#pragma unroll
    for (int j = 0; j < NFR; ++j) {
#pragma unroll
      for (int r = 0; r < 4; ++r) {
        int m = rb * 128 + wr * 64 + i * 16 + lg * 4 + r;
        int n = cb * BN + wc * (BN / 2) + j * 16 + lq;
        float v = acc[i][j][r];
        if (EPI == 0) {
          int which = n >> 10;
          int h = (n >> 6) & 15;
          int d = n & 63;
          int b = m >> 11;
          int tt = m & 2047;
          int bh = b * H_NUM + h;
          if (which == 0) {
            // fold softmax scale AND log2(e) so attention uses exp2 directly
            q_ws[((size_t)bh * T_SEQ + tt) * H_D + d] = f2bf(v * 0.18033688f);
          } else if (which == 1) {
            k_ws[((size_t)bh * T_SEQ + tt) * H_D + d] = f2bf(v);
          } else {
            // V transposed [BH,D,T'] with per-64-tile k-permutation matching
            // the swapped-QK^T in-register P layout (bijective bit shuffle)
            int k0 = tt & 63;
            int tp = (tt & ~63) | ((k0 & 12) << 1) | ((k0 & 48) >> 3) | (k0 & 1) | ((k0 & 2) << 4);
            v_ws[((size_t)bh * H_D + d) * T_SEQ + tp] = f2bf(v);
          }
        } else {
          outf[(size_t)m * 1024 + n] = v;
        }
      }
    }
  }
}

// ---------------------------------------------------------------- flash attention
// (unchanged -- counted-vmcnt 3-buffer pipeline, swapped QK^T in-lane softmax)
__global__ __launch_bounds__(256, 2) void attn_kernel(
    const unsigned short* __restrict__ qw,
    const unsigned short* __restrict__ kw,
    const unsigned short* __restrict__ vtw,
    unsigned short* __restrict__ yw) {
  __shared__ unsigned short kv_lds[3][8192];   // 3 bufs x (K 4096 | V 4096 shorts) = 48KB

  const int bid = blockIdx.x;
  const int bh = (bid & 7) * 8 + ((bid >> 3) & 7);
  const int qblk = bid >> 6;                    // 0..7, 256 rows each

  const int t = threadIdx.x;
  const int w = t >> 6, l = t & 63;
  const int lq = l & 15, lg = l >> 4;
  const int qbase = qblk * 256 + w * 64;
  const size_t head_off = (size_t)bh * T_SEQ * H_D;

  bf16x8 aq[4][2];
#pragma unroll
  for (int qg = 0; qg < 4; ++qg)
#pragma unroll
    for (int kk = 0; kk < 2; ++kk)
      aq[qg][kk] = *reinterpret_cast<const bf16x8*>(
          qw + head_off + (size_t)(qbase + qg * 16 + lq) * H_D + kk * 32 + lg * 8);

  const unsigned short* sbase[4];
  int sstep[4];
#pragma unroll
  for (int i = 0; i < 4; ++i) {
    int c = w * 64 + l + 256 * i;
    if (c < 512) {
      int row = c >> 3, sl = (c & 7) ^ (row & 7);
      sbase[i] = kw + head_off + row * H_D + sl * 8;
      sstep[i] = 64 * H_D;
    } else {
      int c2 = c - 512;
      int row = c2 >> 3, sl = (c2 & 7) ^ (row & 7);
      sbase[i] = vtw + head_off + (size_t)row * T_SEQ + sl * 8;
      sstep[i] = 64;
    }
  }

  unsigned short* bA = &kv_lds[0][0];
  unsigned short* bB = &kv_lds[1][0];
  unsigned short* bC = &kv_lds[2][0];

#define STAGE(KV, DST)                                                              \
  { _Pragma("unroll")                                                               \
    for (int i = 0; i < 4; ++i)                                                     \
      gload_lds16(sbase[i] + (size_t)(KV) * sstep[i], (DST) + (w * 64 + 256 * i) * 8); }

  STAGE(0, bA)
  STAGE(1, bB)

  f32x4 y[4][4] = {};
  float lrow[4] = {0.f, 0.f, 0.f, 0.f};
  union pa_t { bf16x8 v; unsigned int u[4]; };

  for (int kv = 0; kv < T_SEQ / 64; ++kv) {
    if (kv == T_SEQ / 64 - 1) {
      asm volatile("s_waitcnt vmcnt(0)" ::: "memory");
    } else {
      asm volatile("s_waitcnt vmcnt(4)" ::: "memory");
    }
    __builtin_amdgcn_s_barrier();

    bf16x8 kf[8], vf[8];
#pragma unroll
    for (int f = 0; f < 8; ++f) {
      int row = (f >> 1) * 16 + lq;
      int sl = ((f & 1) * 4 + lg) ^ (lq & 7);
      kf[f] = *reinterpret_cast<const bf16x8*>(bA + row * 64 + sl * 8);
    }
#pragma unroll
    for (int db = 0; db < 4; ++db)
#pragma unroll
      for (int ks = 0; ks < 2; ++ks) {
        int row = db * 16 + lq;
        int sl = (ks * 4 + lg) ^ (lq & 7);
        vf[db * 2 + ks] = *reinterpret_cast<const bf16x8*>(bA + 4096 + row * 64 + sl * 8);
      }

    pa_t pa0[4], pa1[4];
#pragma unroll
    for (int qg = 0; qg < 4; ++qg) {
      f32x4 s[4];
#pragma unroll
      for (int tt = 0; tt < 4; ++tt) {
        f32x4 z = {0.f, 0.f, 0.f, 0.f};
        s[tt] = __builtin_amdgcn_mfma_f32_16x16x32_bf16(kf[tt * 2], aq[qg][0], z, 0, 0, 0);
        s[tt] = __builtin_amdgcn_mfma_f32_16x16x32_bf16(kf[tt * 2 + 1], aq[qg][1], s[tt], 0, 0, 0);
      }
      float acc_e = 0.f;
#pragma unroll
      for (int tt = 0; tt < 4; ++tt) {
        float e0 = __builtin_amdgcn_exp2f(s[tt][0]);
        float e1 = __builtin_amdgcn_exp2f(s[tt][1]);
        float e2 = __builtin_amdgcn_exp2f(s[tt][2]);
        float e3 = __builtin_amdgcn_exp2f(s[tt][3]);
        pa0[qg].u[tt] = pack_hi(e0, e1);
        pa1[qg].u[tt] = pack_hi(e2, e3);
        acc_e += (e0 + e1) + (e2 + e3);
      }
      lrow[qg] += acc_e;
    }

#pragma unroll
    for (int qg = 0; qg < 4; ++qg)
#pragma unroll
      for (int db = 0; db < 4; ++db) {
        y[qg][db] = __builtin_amdgcn_mfma_f32_16x16x32_bf16(pa0[qg].v, vf[db * 2], y[qg][db], 0, 0, 0);
        y[qg][db] = __builtin_amdgcn_mfma_f32_16x16x32_bf16(pa1[qg].v, vf[db * 2 + 1], y[qg][db], 0, 0, 0);
      }

    if (kv + 2 < T_SEQ / 64) STAGE(kv + 2, bC)

    unsigned short* tmp = bA; bA = bB; bB = bC; bC = tmp;
  }
#undef STAGE

  const int b = bh >> 4, h = bh & 15;
#pragma unroll
  for (int qg = 0; qg < 4; ++qg) {
    float sm = lrow[qg];
    sm += __shfl_xor(sm, 16);
    sm += __shfl_xor(sm, 32);
    float inv = 1.0f / sm;
#pragma unroll
    for (int r = 0; r < 4; ++r) {
      float iv = __shfl(inv, lg * 4 + r);
      int row = qbase + qg * 16 + lg * 4 + r;
#pragma unroll
      for (int db = 0; db < 4; ++db) {
        int d = db * 16 + lq;
        yw[((size_t)(b * T_SEQ + row)) * C_DIM + h * 64 + d] = f2bf(y[qg][db][r] * iv);
      }
    }
  }
}

// ---------------------------------------------------------------- launch
extern "C" void kernel_launch(void* const* d_in, const int* in_sizes, int n_in,
                              void* d_out, int out_size, void* d_ws, size_t ws_size,
                              hipStream_t stream) {
  (void)in_sizes; (void)n_in; (void)out_size; (void)ws_size;
  const float* x      = (const float*)d_in[0];
  const float* w_attn = (const float*)d_in[1];
  const float* w_proj = (const float*)d_in[2];
  float* out = (float*)d_out;

  unsigned short* ws = (unsigned short*)d_ws;
  const size_t XB = (size_t)M_ROWS * C_DIM;          // 8,388,608
  unsigned short* xb  = ws;                          // x bf16 [8192,1024]; reused as y after attn
  unsigned short* wab = xb + XB;                     // w_attn bf16 [3072,1024]
  unsigned short* wpb = wab + (size_t)3072 * 1024;   // w_proj bf16 [1024,1024]
  unsigned short* qws = wpb + (size_t)1024 * 1024;   // q [BH,T,D] (pre-scaled by 0.125*log2e)
  unsigned short* kws = qws + XB;                    // k [BH,T,D]
  unsigned short* vws = kws + XB;                    // v^T [BH,D,T'] k-permuted
  unsigned short* yws = xb;                          // attention output [B,T,C] (xb dead by then)

  cast_all_kernel<<<3145728 / 256, 256, 0, stream>>>(x, w_attn, w_proj, xb, wab, wpb);

  gemm_bt_kernel<0><<<1024, 256, 0, stream>>>(xb, wab, qws, kws, vws, nullptr);
  attn_kernel<<<512, 256, 0, stream>>>(qws, kws, vws, yws);
  gemm_bt_kernel<1><<<1024, 256, 0, stream>>>(yws, wpb, nullptr, nullptr, nullptr, out);
}

// Round 6
// 190.794 us; speedup vs baseline: 1.3228x; 1.3228x over previous
//
#include <hip/hip_runtime.h>

// Problem constants
#define T_SEQ 2048
#define C_DIM 1024
#define H_NUM 16
#define H_D   64
#define B_NUM 4
#define M_ROWS 8192   // B*T

typedef __attribute__((ext_vector_type(4))) float f32x4;
typedef __attribute__((ext_vector_type(8))) short bf16x8;   // 8 bf16 = 4 VGPRs

__device__ __forceinline__ unsigned short f2bf(float f) {
  union { float f; unsigned int u; } a;
  a.f = f;
  unsigned int u = a.u;
  u += 0x7fffu + ((u >> 16) & 1u);   // RNE
  return (unsigned short)(u >> 16);
}

__device__ __forceinline__ unsigned int fbits(float f) {
  union { float f; unsigned int u; } a; a.f = f; return a.u;
}

// pack the high halves (bf16-truncate) of two f32 into one u32: {hi(b), hi(a)}
__device__ __forceinline__ unsigned int pack_hi(float a, float b) {
#if __has_builtin(__builtin_amdgcn_perm)
  return __builtin_amdgcn_perm(fbits(b), fbits(a), 0x07060302u);  // 1 VALU op
#else
  return (fbits(b) & 0xffff0000u) | (fbits(a) >> 16);
#endif
}

// async global->LDS, 16B per lane; LDS dest = wave-uniform base + lane*16
__device__ __forceinline__ void gload_lds16(const unsigned short* g, unsigned short* l) {
  __builtin_amdgcn_global_load_lds(
      (const __attribute__((address_space(1))) unsigned int*)g,
      (__attribute__((address_space(3))) unsigned int*)l, 16, 0, 0);
}

// ---------------------------------------------------------------- fused cast fp32 -> bf16
__global__ __launch_bounds__(256) void cast_all_kernel(const float* __restrict__ x,
                                                       const float* __restrict__ wa,
                                                       const float* __restrict__ wp,
                                                       unsigned short* __restrict__ xb,
                                                       unsigned short* __restrict__ wab,
                                                       unsigned short* __restrict__ wpb) {
  int i = blockIdx.x * 256 + threadIdx.x;
  const float* src;
  unsigned short* dst;
  int off;
  if (i < 2097152) {           // x: 8192*1024/4
    src = x; dst = xb; off = i;
  } else if (i < 2883584) {    // w_attn: 3072*1024/4
    src = wa; dst = wab; off = i - 2097152;
  } else {                     // w_proj: 1024*1024/4
    src = wp; dst = wpb; off = i - 2883584;
  }
  float4 v = reinterpret_cast<const float4*>(src)[off];
  ushort4 o;
  o.x = f2bf(v.x); o.y = f2bf(v.y); o.z = f2bf(v.z); o.w = f2bf(v.w);
  reinterpret_cast<ushort4*>(dst)[off] = o;
}

// ---------------------------------------------------------------- GEMM0 (QKV)
// Round 6: escape the VGPR cap on intensity via THREAD COUNT, not per-thread
// registers. Round-5's BN=192 @256thr spilled (needs ~136 regs vs 128 cap ->
// WRITE_SIZE 245MB scratch). This kernel: 256x192 tile @ 512 threads, 8 waves
// (2M x 4N) -- EXACTLY round-2's register geometry (measured 100 VGPR, no
// spill) attached to the PROVEN 2-phase loop body (rounds 0/3/4, 0 bank
// conflicts). Intensity 256*192/448 = 109.7 (2x round-4's 54.9).
// LDS (256+192)*64*2 = 56KB -> 2 blocks/CU (launch_bounds(512,4), cap 128).
// Grid 32x16 = 512 = EXACTLY one resident round at 2 blocks/CU.
// Swizzle verbatim: pre-swizzled global source + linear LDS dest + swizzled
// ds_read (slot ^ (row&7)).
// Epilogue: q*0.125*log2e, k [BH,T,D], v^T [BH,D,T'] k-permuted (unchanged).
__global__ __launch_bounds__(512, 4) void gemm_qkv_kernel(
    const unsigned short* __restrict__ A,
    const unsigned short* __restrict__ Bw,
    unsigned short* __restrict__ q_ws,
    unsigned short* __restrict__ k_ws,
    unsigned short* __restrict__ v_ws) {
  constexpr int KK = 1024;
  constexpr int KT = KK / 64;            // 16

  __shared__ unsigned short lds[16384 + 12288];   // A 32KB | B 24KB = 56KB

  // T1 bijective XCD swizzle (NWG = 512, %8 == 0)
  const int bid = blockIdx.x;
  const int logical = (bid & 7) * 64 + (bid >> 3);
  const int rb = logical >> 4, cb = logical & 15;   // 32 x 16

  const int t = threadIdx.x;
  const int w = t >> 6, l = t & 63;
  const int wr = w >> 2, wc = w & 3;     // 2M x 4N wave grid
  const int lq = l & 15, lg = l >> 4;

  const size_t a_base = (size_t)(rb * 256) * KK;
  const size_t b_base = (size_t)(cb * 192) * KK;

  // staging chunk c = t + 512*i -> (row=c>>3, slot=c&7), src slot ^= row&7
  int aRow[4], aGs[4];
#pragma unroll
  for (int i = 0; i < 4; ++i) {
    int c = t + 512 * i;
    aRow[i] = c >> 3;                    // 0..255
    aGs[i] = (c & 7) ^ (aRow[i] & 7);
  }
  int bRow[3], bGs[3];
#pragma unroll
  for (int i = 0; i < 3; ++i) {
    int c = t + 512 * i;
    bRow[i] = c >> 3;                    // 0..191
    bGs[i] = (c & 7) ^ (bRow[i] & 7);
  }

  f32x4 acc[8][3] = {};

  for (int kt = 0; kt < KT; ++kt) {
    const int ko = kt * 64;
#pragma unroll
    for (int i = 0; i < 4; ++i)
      gload_lds16(A + a_base + (size_t)aRow[i] * KK + ko + aGs[i] * 8,
                  &lds[(t + 512 * i) * 8]);
#pragma unroll
    for (int i = 0; i < 3; ++i)
      gload_lds16(Bw + b_base + (size_t)bRow[i] * KK + ko + bGs[i] * 8,
                  &lds[16384 + (t + 512 * i) * 8]);
    __syncthreads();   // drains vmcnt -> tile kt fully in LDS

#pragma unroll
    for (int kk = 0; kk < 2; ++kk) {
      const int sg = kk * 4 + lg;
      bf16x8 bfv[3];
#pragma unroll
      for (int j = 0; j < 3; ++j) {
        int R = wc * 48 + j * 16 + lq;
        bfv[j] = *reinterpret_cast<const bf16x8*>(&lds[16384 + (R * 8 + (sg ^ (R & 7))) * 8]);
      }
#pragma unroll
      for (int mq = 0; mq < 2; ++mq) {
        bf16x8 af[4];
#pragma unroll
        for (int i = 0; i < 4; ++i) {
          int R = wr * 128 + mq * 64 + i * 16 + lq;
          af[i] = *reinterpret_cast<const bf16x8*>(&lds[(R * 8 + (sg ^ (R & 7))) * 8]);
        }
#pragma unroll
        for (int i = 0; i < 4; ++i)
#pragma unroll
          for (int j = 0; j < 3; ++j)
            acc[mq * 4 + i][j] =
                __builtin_amdgcn_mfma_f32_16x16x32_bf16(af[i], bfv[j], acc[mq * 4 + i][j], 0, 0, 0);
      }
    }
    __syncthreads();   // WAR before next stage
  }

  // epilogue: C/D layout col = lane&15, row = (lane>>4)*4 + reg  (m89-verified)
#pragma unroll
  for (int f = 0; f < 8; ++f) {
#pragma unroll
    for (int j = 0; j < 3; ++j) {
#pragma unroll
      for (int r = 0; r < 4; ++r) {
        int m = rb * 256 + wr * 128 + f * 16 + lg * 4 + r;
        int n = cb * 192 + wc * 48 + j * 16 + lq;
        float v = acc[f][j][r];
        int which = n >> 10;
        int h = (n >> 6) & 15;
        int d = n & 63;
        int b = m >> 11;
        int tt = m & 2047;
        int bh = b * H_NUM + h;
        if (which == 0) {
          // fold softmax scale AND log2(e) so attention uses exp2 directly
          q_ws[((size_t)bh * T_SEQ + tt) * H_D + d] = f2bf(v * 0.18033688f);
        } else if (which == 1) {
          k_ws[((size_t)bh * T_SEQ + tt) * H_D + d] = f2bf(v);
        } else {
          // V transposed [BH,D,T'] with per-64-tile k-permutation matching
          // the swapped-QK^T in-register P layout (bijective bit shuffle)
          int k0 = tt & 63;
          int tp = (tt & ~63) | ((k0 & 12) << 1) | ((k0 & 48) >> 3) | (k0 & 1) | ((k0 & 2) << 4);
          v_ws[((size_t)bh * H_D + d) * T_SEQ + tp] = f2bf(v);
        }
      }
    }
  }
}

// ---------------------------------------------------------------- GEMM1  out = y * Wp^T
// Round-0's measured-best EPI1 config (128x128, grid 512) + T1 swizzle.
__global__ __launch_bounds__(256, 4) void gemm_proj_kernel(
    const unsigned short* __restrict__ A,
    const unsigned short* __restrict__ Bw,
    float* __restrict__ outf) {
  constexpr int KK = 1024;
  constexpr int KT = KK / 64;

  __shared__ unsigned short lds[16384];   // A 16KB | B 16KB

  const int bid = blockIdx.x;             // NWG = 512
  const int logical = (bid & 7) * 64 + (bid >> 3);
  const int rb = logical >> 3, cb = logical & 7;   // 64 x 8

  const int t = threadIdx.x;
  const int w = t >> 6, l = t & 63;
  const int wr = w >> 1, wc = w & 1;
  const int lq = l & 15, lg = l >> 4;

  const size_t a_base = (size_t)(rb * 128) * KK;
  const size_t b_base = (size_t)(cb * 128) * KK;

  int s_row[4], s_gs[4];
#pragma unroll
  for (int i = 0; i < 4; ++i) {
    int c = t + 256 * i;
    s_row[i] = c >> 3;
    s_gs[i] = (c & 7) ^ (s_row[i] & 7);
  }

  f32x4 acc[4][4] = {};

  for (int kt = 0; kt < KT; ++kt) {
    const int ko = kt * 64;
#pragma unroll
    for (int i = 0; i < 4; ++i) {
      unsigned short* la = &lds[(t + 256 * i) * 8];
      gload_lds16(A + a_base + (size_t)s_row[i] * KK + ko + s_gs[i] * 8, la);
      gload_lds16(Bw + b_base + (size_t)s_row[i] * KK + ko + s_gs[i] * 8, la + 8192);
    }
    __syncthreads();

#pragma unroll
    for (int kk = 0; kk < 2; ++kk) {
      const int sg = kk * 4 + lg;
      bf16x8 af[4], bfv[4];
#pragma unroll
      for (int i = 0; i < 4; ++i) {
        int R = wr * 64 + i * 16 + lq;
        af[i] = *reinterpret_cast<const bf16x8*>(&lds[(R * 8 + (sg ^ (R & 7))) * 8]);
      }
#pragma unroll
      for (int j = 0; j < 4; ++j) {
        int R = wc * 64 + j * 16 + lq;
        bfv[j] = *reinterpret_cast<const bf16x8*>(&lds[8192 + (R * 8 + (sg ^ (R & 7))) * 8]);
      }
#pragma unroll
      for (int i = 0; i < 4; ++i)
#pragma unroll
        for (int j = 0; j < 4; ++j)
          acc[i][j] = __builtin_amdgcn_mfma_f32_16x16x32_bf16(af[i], bfv[j], acc[i][j], 0, 0, 0);
    }
    __syncthreads();
  }

#pragma unroll
  for (int i = 0; i < 4; ++i)
#pragma unroll
    for (int j = 0; j < 4; ++j)
#pragma unroll
      for (int r = 0; r < 4; ++r) {
        int m = rb * 128 + wr * 64 + i * 16 + lg * 4 + r;
        int n = cb * 128 + wc * 64 + j * 16 + lq;
        outf[(size_t)m * 1024 + n] = acc[i][j][r];
      }
}

// ---------------------------------------------------------------- flash attention
// (unchanged -- counted-vmcnt 3-buffer pipeline, swapped QK^T in-lane softmax)
__global__ __launch_bounds__(256, 2) void attn_kernel(
    const unsigned short* __restrict__ qw,
    const unsigned short* __restrict__ kw,
    const unsigned short* __restrict__ vtw,
    unsigned short* __restrict__ yw) {
  __shared__ unsigned short kv_lds[3][8192];   // 3 bufs x (K 4096 | V 4096 shorts) = 48KB

  const int bid = blockIdx.x;
  const int bh = (bid & 7) * 8 + ((bid >> 3) & 7);
  const int qblk = bid >> 6;                    // 0..7, 256 rows each

  const int t = threadIdx.x;
  const int w = t >> 6, l = t & 63;
  const int lq = l & 15, lg = l >> 4;
  const int qbase = qblk * 256 + w * 64;
  const size_t head_off = (size_t)bh * T_SEQ * H_D;

  bf16x8 aq[4][2];
#pragma unroll
  for (int qg = 0; qg < 4; ++qg)
#pragma unroll
    for (int kk = 0; kk < 2; ++kk)
      aq[qg][kk] = *reinterpret_cast<const bf16x8*>(
          qw + head_off + (size_t)(qbase + qg * 16 + lq) * H_D + kk * 32 + lg * 8);

  const unsigned short* sbase[4];
  int sstep[4];
#pragma unroll
  for (int i = 0; i < 4; ++i) {
    int c = w * 64 + l + 256 * i;
    if (c < 512) {
      int row = c >> 3, sl = (c & 7) ^ (row & 7);
      sbase[i] = kw + head_off + row * H_D + sl * 8;
      sstep[i] = 64 * H_D;
    } else {
      int c2 = c - 512;
      int row = c2 >> 3, sl = (c2 & 7) ^ (row & 7);
      sbase[i] = vtw + head_off + (size_t)row * T_SEQ + sl * 8;
      sstep[i] = 64;
    }
  }

  unsigned short* bA = &kv_lds[0][0];
  unsigned short* bB = &kv_lds[1][0];
  unsigned short* bC = &kv_lds[2][0];

#define STAGE(KV, DST)                                                              \
  { _Pragma("unroll")                                                               \
    for (int i = 0; i < 4; ++i)                                                     \
      gload_lds16(sbase[i] + (size_t)(KV) * sstep[i], (DST) + (w * 64 + 256 * i) * 8); }

  STAGE(0, bA)
  STAGE(1, bB)

  f32x4 y[4][4] = {};
  float lrow[4] = {0.f, 0.f, 0.f, 0.f};
  union pa_t { bf16x8 v; unsigned int u[4]; };

  for (int kv = 0; kv < T_SEQ / 64; ++kv) {
    if (kv == T_SEQ / 64 - 1) {
      asm volatile("s_waitcnt vmcnt(0)" ::: "memory");
    } else {
      asm volatile("s_waitcnt vmcnt(4)" ::: "memory");
    }
    __builtin_amdgcn_s_barrier();

    bf16x8 kf[8], vf[8];
#pragma unroll
    for (int f = 0; f < 8; ++f) {
      int row = (f >> 1) * 16 + lq;
      int sl = ((f & 1) * 4 + lg) ^ (lq & 7);
      kf[f] = *reinterpret_cast<const bf16x8*>(bA + row * 64 + sl * 8);
    }
#pragma unroll
    for (int db = 0; db < 4; ++db)
#pragma unroll
      for (int ks = 0; ks < 2; ++ks) {
        int row = db * 16 + lq;
        int sl = (ks * 4 + lg) ^ (lq & 7);
        vf[db * 2 + ks] = *reinterpret_cast<const bf16x8*>(bA + 4096 + row * 64 + sl * 8);
      }

    pa_t pa0[4], pa1[4];
#pragma unroll
    for (int qg = 0; qg < 4; ++qg) {
      f32x4 s[4];
#pragma unroll
      for (int tt = 0; tt < 4; ++tt) {
        f32x4 z = {0.f, 0.f, 0.f, 0.f};
        s[tt] = __builtin_amdgcn_mfma_f32_16x16x32_bf16(kf[tt * 2], aq[qg][0], z, 0, 0, 0);
        s[tt] = __builtin_amdgcn_mfma_f32_16x16x32_bf16(kf[tt * 2 + 1], aq[qg][1], s[tt], 0, 0, 0);
      }
      float acc_e = 0.f;
#pragma unroll
      for (int tt = 0; tt < 4; ++tt) {
        float e0 = __builtin_amdgcn_exp2f(s[tt][0]);
        float e1 = __builtin_amdgcn_exp2f(s[tt][1]);
        float e2 = __builtin_amdgcn_exp2f(s[tt][2]);
        float e3 = __builtin_amdgcn_exp2f(s[tt][3]);
        pa0[qg].u[tt] = pack_hi(e0, e1);
        pa1[qg].u[tt] = pack_hi(e2, e3);
        acc_e += (e0 + e1) + (e2 + e3);
      }
      lrow[qg] += acc_e;
    }

#pragma unroll
    for (int qg = 0; qg < 4; ++qg)
#pragma unroll
      for (int db = 0; db < 4; ++db) {
        y[qg][db] = __builtin_amdgcn_mfma_f32_16x16x32_bf16(pa0[qg].v, vf[db * 2], y[qg][db], 0, 0, 0);
        y[qg][db] = __builtin_amdgcn_mfma_f32_16x16x32_bf16(pa1[qg].v, vf[db * 2 + 1], y[qg][db], 0, 0, 0);
      }

    if (kv + 2 < T_SEQ / 64) STAGE(kv + 2, bC)

    unsigned short* tmp = bA; bA = bB; bB = bC; bC = tmp;
  }
#undef STAGE

  const int b = bh >> 4, h = bh & 15;
#pragma unroll
  for (int qg = 0; qg < 4; ++qg) {
    float sm = lrow[qg];
    sm += __shfl_xor(sm, 16);
    sm += __shfl_xor(sm, 32);
    float inv = 1.0f / sm;
#pragma unroll
    for (int r = 0; r < 4; ++r) {
      float iv = __shfl(inv, lg * 4 + r);
      int row = qbase + qg * 16 + lg * 4 + r;
#pragma unroll
      for (int db = 0; db < 4; ++db) {
        int d = db * 16 + lq;
        yw[((size_t)(b * T_SEQ + row)) * C_DIM + h * 64 + d] = f2bf(y[qg][db][r] * iv);
      }
    }
  }
}

// ---------------------------------------------------------------- launch
extern "C" void kernel_launch(void* const* d_in, const int* in_sizes, int n_in,
                              void* d_out, int out_size, void* d_ws, size_t ws_size,
                              hipStream_t stream) {
  (void)in_sizes; (void)n_in; (void)out_size; (void)ws_size;
  const float* x      = (const float*)d_in[0];
  const float* w_attn = (const float*)d_in[1];
  const float* w_proj = (const float*)d_in[2];
  float* out = (float*)d_out;

  unsigned short* ws = (unsigned short*)d_ws;
  const size_t XB = (size_t)M_ROWS * C_DIM;          // 8,388,608
  unsigned short* xb  = ws;                          // x bf16 [8192,1024]; reused as y after attn
  unsigned short* wab = xb + XB;                     // w_attn bf16 [3072,1024]
  unsigned short* wpb = wab + (size_t)3072 * 1024;   // w_proj bf16 [1024,1024]
  unsigned short* qws = wpb + (size_t)1024 * 1024;   // q [BH,T,D] (pre-scaled by 0.125*log2e)
  unsigned short* kws = qws + XB;                    // k [BH,T,D]
  unsigned short* vws = kws + XB;                    // v^T [BH,D,T'] k-permuted
  unsigned short* yws = xb;                          // attention output [B,T,C] (xb dead by then)

  cast_all_kernel<<<3145728 / 256, 256, 0, stream>>>(x, w_attn, w_proj, xb, wab, wpb);

  gemm_qkv_kernel<<<512, 512, 0, stream>>>(xb, wab, qws, kws, vws);
  attn_kernel<<<512, 256, 0, stream>>>(qws, kws, vws, yws);
  gemm_proj_kernel<<<512, 256, 0, stream>>>(yws, wpb, out);
}

// Round 7
// 182.030 us; speedup vs baseline: 1.3865x; 1.0481x over previous
//
#include <hip/hip_runtime.h>

// Problem constants
#define T_SEQ 2048
#define C_DIM 1024
#define H_NUM 16
#define H_D   64
#define B_NUM 4
#define M_ROWS 8192   // B*T

typedef __attribute__((ext_vector_type(4))) float f32x4;
typedef __attribute__((ext_vector_type(8))) short bf16x8;   // 8 bf16 = 4 VGPRs

__device__ __forceinline__ unsigned short f2bf(float f) {
  union { float f; unsigned int u; } a;
  a.f = f;
  unsigned int u = a.u;
  u += 0x7fffu + ((u >> 16) & 1u);   // RNE
  return (unsigned short)(u >> 16);
}

__device__ __forceinline__ unsigned int fbits(float f) {
  union { float f; unsigned int u; } a; a.f = f; return a.u;
}

// pack the high halves (bf16-truncate) of two f32 into one u32: {hi(b), hi(a)}
__device__ __forceinline__ unsigned int pack_hi(float a, float b) {
#if __has_builtin(__builtin_amdgcn_perm)
  return __builtin_amdgcn_perm(fbits(b), fbits(a), 0x07060302u);  // 1 VALU op
#else
  return (fbits(b) & 0xffff0000u) | (fbits(a) >> 16);
#endif
}

// async global->LDS, 16B per lane; LDS dest = wave-uniform base + lane*16
__device__ __forceinline__ void gload_lds16(const unsigned short* g, unsigned short* l) {
  __builtin_amdgcn_global_load_lds(
      (const __attribute__((address_space(1))) unsigned int*)g,
      (__attribute__((address_space(3))) unsigned int*)l, 16, 0, 0);
}

// ---------------------------------------------------------------- fused cast fp32 -> bf16
__global__ __launch_bounds__(256) void cast_all_kernel(const float* __restrict__ x,
                                                       const float* __restrict__ wa,
                                                       const float* __restrict__ wp,
                                                       unsigned short* __restrict__ xb,
                                                       unsigned short* __restrict__ wab,
                                                       unsigned short* __restrict__ wpb) {
  int i = blockIdx.x * 256 + threadIdx.x;
  const float* src;
  unsigned short* dst;
  int off;
  if (i < 2097152) {           // x: 8192*1024/4
    src = x; dst = xb; off = i;
  } else if (i < 2883584) {    // w_attn: 3072*1024/4
    src = wa; dst = wab; off = i - 2097152;
  } else {                     // w_proj: 1024*1024/4
    src = wp; dst = wpb; off = i - 2883584;
  }
  float4 v = reinterpret_cast<const float4*>(src)[off];
  ushort4 o;
  o.x = f2bf(v.x); o.y = f2bf(v.y); o.z = f2bf(v.z); o.w = f2bf(v.w);
  reinterpret_cast<ushort4*>(dst)[off] = o;
}

// ---------------------------------------------------------------- GEMM0 (QKV)
// Round 7: intensity scaling done LEGALLY under the unified-register law
// derived from rounds 0/4/5/6: rocprof VGPR_Count excludes the AGPR-side
// accumulator (unified gfx950 file); under a 4-waves/EU cap the budget is
// 128 total -> per-thread acc must be <= ~64 f32. r5 (acc 96 @256thr) and
// r6 (acc 96 @512thr) both spilled (WRITE_SIZE 245/107 MB scratch); the
// intensity model was never actually tested.
// This kernel: 256x128 tile @ 512 threads, 8 waves in 4M x 2N -> per-wave
// 64x64 = round-0's exact verified fragment geometry (acc[4][4]=64 AGPR,
// af[4]+bfv[4] in ~60 VGPRs -> 124 <= 128, r0-proven margin).
// Intensity 256*128/384 = 85.3 (1.55x round-4). Staged volume 939->604 MB
// (round-4 ran at ~10.3 TB/s L3-side delivery -- likely the binding rate).
// LDS (256+128)*64*2 = 48KB -> 2 blocks/CU = 16 waves/CU (round-4 TLP).
// Grid 32x24 = 768 (%8==0 -> bijective XCD swizzle; 1.5 rounds accepted).
// Loop body / swizzle / epilogue verbatim from the verified kernel.
__global__ __launch_bounds__(512, 4) void gemm_qkv_kernel(
    const unsigned short* __restrict__ A,
    const unsigned short* __restrict__ Bw,
    unsigned short* __restrict__ q_ws,
    unsigned short* __restrict__ k_ws,
    unsigned short* __restrict__ v_ws) {
  constexpr int KK = 1024;
  constexpr int KT = KK / 64;            // 16

  __shared__ unsigned short lds[16384 + 8192];   // A 32KB | B 16KB = 48KB

  // T1 bijective XCD swizzle (NWG = 768, %8 == 0)
  const int bid = blockIdx.x;
  const int logical = (bid & 7) * 96 + (bid >> 3);
  const int rb = logical / 24, cb = logical % 24;   // 32 x 24

  const int t = threadIdx.x;
  const int w = t >> 6, l = t & 63;
  const int wr = w >> 1, wc = w & 1;     // 4M x 2N wave grid
  const int lq = l & 15, lg = l >> 4;

  const size_t a_base = (size_t)(rb * 256) * KK;
  const size_t b_base = (size_t)(cb * 128) * KK;

  // staging chunk c -> (row=c>>3, slot=c&7), src slot ^= row&7
  int aRow[4], aGs[4];
#pragma unroll
  for (int i = 0; i < 4; ++i) {
    int c = t + 512 * i;
    aRow[i] = c >> 3;                    // 0..255
    aGs[i] = (c & 7) ^ (aRow[i] & 7);
  }
  int bRow[2], bGs[2];
#pragma unroll
  for (int i = 0; i < 2; ++i) {
    int c = t + 512 * i;
    bRow[i] = c >> 3;                    // 0..127
    bGs[i] = (c & 7) ^ (bRow[i] & 7);
  }

  f32x4 acc[4][4] = {};

  for (int kt = 0; kt < KT; ++kt) {
    const int ko = kt * 64;
#pragma unroll
    for (int i = 0; i < 4; ++i)
      gload_lds16(A + a_base + (size_t)aRow[i] * KK + ko + aGs[i] * 8,
                  &lds[(t + 512 * i) * 8]);
#pragma unroll
    for (int i = 0; i < 2; ++i)
      gload_lds16(Bw + b_base + (size_t)bRow[i] * KK + ko + bGs[i] * 8,
                  &lds[16384 + (t + 512 * i) * 8]);
    __syncthreads();   // drains vmcnt -> tile kt fully in LDS

#pragma unroll
    for (int kk = 0; kk < 2; ++kk) {
      const int sg = kk * 4 + lg;
      bf16x8 af[4], bfv[4];
#pragma unroll
      for (int i = 0; i < 4; ++i) {
        int R = wr * 64 + i * 16 + lq;   // 0..255
        af[i] = *reinterpret_cast<const bf16x8*>(&lds[(R * 8 + (sg ^ (R & 7))) * 8]);
      }
#pragma unroll
      for (int j = 0; j < 4; ++j) {
        int R = wc * 64 + j * 16 + lq;   // 0..127
        bfv[j] = *reinterpret_cast<const bf16x8*>(&lds[16384 + (R * 8 + (sg ^ (R & 7))) * 8]);
      }
#pragma unroll
      for (int i = 0; i < 4; ++i)
#pragma unroll
        for (int j = 0; j < 4; ++j)
          acc[i][j] = __builtin_amdgcn_mfma_f32_16x16x32_bf16(af[i], bfv[j], acc[i][j], 0, 0, 0);
    }
    __syncthreads();   // WAR before next stage
  }

  // epilogue: C/D layout col = lane&15, row = (lane>>4)*4 + reg  (m89-verified)
#pragma unroll
  for (int i = 0; i < 4; ++i) {
#pragma unroll
    for (int j = 0; j < 4; ++j) {
#pragma unroll
      for (int r = 0; r < 4; ++r) {
        int m = rb * 256 + wr * 64 + i * 16 + lg * 4 + r;
        int n = cb * 128 + wc * 64 + j * 16 + lq;
        float v = acc[i][j][r];
        int which = n >> 10;
        int h = (n >> 6) & 15;
        int d = n & 63;
        int b = m >> 11;
        int tt = m & 2047;
        int bh = b * H_NUM + h;
        if (which == 0) {
          // fold softmax scale AND log2(e) so attention uses exp2 directly
          q_ws[((size_t)bh * T_SEQ + tt) * H_D + d] = f2bf(v * 0.18033688f);
        } else if (which == 1) {
          k_ws[((size_t)bh * T_SEQ + tt) * H_D + d] = f2bf(v);
        } else {
          // V transposed [BH,D,T'] with per-64-tile k-permutation matching
          // the swapped-QK^T in-register P layout (bijective bit shuffle)
          int k0 = tt & 63;
          int tp = (tt & ~63) | ((k0 & 12) << 1) | ((k0 & 48) >> 3) | (k0 & 1) | ((k0 & 2) << 4);
          v_ws[((size_t)bh * H_D + d) * T_SEQ + tp] = f2bf(v);
        }
      }
    }
  }
}

// ---------------------------------------------------------------- GEMM1  out = y * Wp^T
// Round-0's measured-best EPI1 config (128x128, grid 512) + T1 swizzle.
__global__ __launch_bounds__(256, 4) void gemm_proj_kernel(
    const unsigned short* __restrict__ A,
    const unsigned short* __restrict__ Bw,
    float* __restrict__ outf) {
  constexpr int KK = 1024;
  constexpr int KT = KK / 64;

  __shared__ unsigned short lds[16384];   // A 16KB | B 16KB

  const int bid = blockIdx.x;             // NWG = 512
  const int logical = (bid & 7) * 64 + (bid >> 3);
  const int rb = logical >> 3, cb = logical & 7;   // 64 x 8

  const int t = threadIdx.x;
  const int w = t >> 6, l = t & 63;
  const int wr = w >> 1, wc = w & 1;
  const int lq = l & 15, lg = l >> 4;

  const size_t a_base = (size_t)(rb * 128) * KK;
  const size_t b_base = (size_t)(cb * 128) * KK;

  int s_row[4], s_gs[4];
#pragma unroll
  for (int i = 0; i < 4; ++i) {
    int c = t + 256 * i;
    s_row[i] = c >> 3;
    s_gs[i] = (c & 7) ^ (s_row[i] & 7);
  }

  f32x4 acc[4][4] = {};

  for (int kt = 0; kt < KT; ++kt) {
    const int ko = kt * 64;
#pragma unroll
    for (int i = 0; i < 4; ++i) {
      unsigned short* la = &lds[(t + 256 * i) * 8];
      gload_lds16(A + a_base + (size_t)s_row[i] * KK + ko + s_gs[i] * 8, la);
      gload_lds16(Bw + b_base + (size_t)s_row[i] * KK + ko + s_gs[i] * 8, la + 8192);
    }
    __syncthreads();

#pragma unroll
    for (int kk = 0; kk < 2; ++kk) {
      const int sg = kk * 4 + lg;
      bf16x8 af[4], bfv[4];
#pragma unroll
      for (int i = 0; i < 4; ++i) {
        int R = wr * 64 + i * 16 + lq;
        af[i] = *reinterpret_cast<const bf16x8*>(&lds[(R * 8 + (sg ^ (R & 7))) * 8]);
      }
#pragma unroll
      for (int j = 0; j < 4; ++j) {
        int R = wc * 64 + j * 16 + lq;
        bfv[j] = *reinterpret_cast<const bf16x8*>(&lds[8192 + (R * 8 + (sg ^ (R & 7))) * 8]);
      }
#pragma unroll
      for (int i = 0; i < 4; ++i)
#pragma unroll
        for (int j = 0; j < 4; ++j)
          acc[i][j] = __builtin_amdgcn_mfma_f32_16x16x32_bf16(af[i], bfv[j], acc[i][j], 0, 0, 0);
    }
    __syncthreads();
  }

#pragma unroll
  for (int i = 0; i < 4; ++i)
#pragma unroll
    for (int j = 0; j < 4; ++j)
#pragma unroll
      for (int r = 0; r < 4; ++r) {
        int m = rb * 128 + wr * 64 + i * 16 + lg * 4 + r;
        int n = cb * 128 + wc * 64 + j * 16 + lq;
        outf[(size_t)m * 1024 + n] = acc[i][j][r];
      }
}

// ---------------------------------------------------------------- flash attention
// (unchanged -- counted-vmcnt 3-buffer pipeline, swapped QK^T in-lane softmax)
__global__ __launch_bounds__(256, 2) void attn_kernel(
    const unsigned short* __restrict__ qw,
    const unsigned short* __restrict__ kw,
    const unsigned short* __restrict__ vtw,
    unsigned short* __restrict__ yw) {
  __shared__ unsigned short kv_lds[3][8192];   // 3 bufs x (K 4096 | V 4096 shorts) = 48KB

  const int bid = blockIdx.x;
  const int bh = (bid & 7) * 8 + ((bid >> 3) & 7);
  const int qblk = bid >> 6;                    // 0..7, 256 rows each

  const int t = threadIdx.x;
  const int w = t >> 6, l = t & 63;
  const int lq = l & 15, lg = l >> 4;
  const int qbase = qblk * 256 + w * 64;
  const size_t head_off = (size_t)bh * T_SEQ * H_D;

  bf16x8 aq[4][2];
#pragma unroll
  for (int qg = 0; qg < 4; ++qg)
#pragma unroll
    for (int kk = 0; kk < 2; ++kk)
      aq[qg][kk] = *reinterpret_cast<const bf16x8*>(
          qw + head_off + (size_t)(qbase + qg * 16 + lq) * H_D + kk * 32 + lg * 8);

  const unsigned short* sbase[4];
  int sstep[4];
#pragma unroll
  for (int i = 0; i < 4; ++i) {
    int c = w * 64 + l + 256 * i;
    if (c < 512) {
      int row = c >> 3, sl = (c & 7) ^ (row & 7);
      sbase[i] = kw + head_off + row * H_D + sl * 8;
      sstep[i] = 64 * H_D;
    } else {
      int c2 = c - 512;
      int row = c2 >> 3, sl = (c2 & 7) ^ (row & 7);
      sbase[i] = vtw + head_off + (size_t)row * T_SEQ + sl * 8;
      sstep[i] = 64;
    }
  }

  unsigned short* bA = &kv_lds[0][0];
  unsigned short* bB = &kv_lds[1][0];
  unsigned short* bC = &kv_lds[2][0];

#define STAGE(KV, DST)                                                              \
  { _Pragma("unroll")                                                               \
    for (int i = 0; i < 4; ++i)                                                     \
      gload_lds16(sbase[i] + (size_t)(KV) * sstep[i], (DST) + (w * 64 + 256 * i) * 8); }

  STAGE(0, bA)
  STAGE(1, bB)

  f32x4 y[4][4] = {};
  float lrow[4] = {0.f, 0.f, 0.f, 0.f};
  union pa_t { bf16x8 v; unsigned int u[4]; };

  for (int kv = 0; kv < T_SEQ / 64; ++kv) {
    if (kv == T_SEQ / 64 - 1) {
      asm volatile("s_waitcnt vmcnt(0)" ::: "memory");
    } else {
      asm volatile("s_waitcnt vmcnt(4)" ::: "memory");
    }
    __builtin_amdgcn_s_barrier();

    bf16x8 kf[8], vf[8];
#pragma unroll
    for (int f = 0; f < 8; ++f) {
      int row = (f >> 1) * 16 + lq;
      int sl = ((f & 1) * 4 + lg) ^ (lq & 7);
      kf[f] = *reinterpret_cast<const bf16x8*>(bA + row * 64 + sl * 8);
    }
#pragma unroll
    for (int db = 0; db < 4; ++db)
#pragma unroll
      for (int ks = 0; ks < 2; ++ks) {
        int row = db * 16 + lq;
        int sl = (ks * 4 + lg) ^ (lq & 7);
        vf[db * 2 + ks] = *reinterpret_cast<const bf16x8*>(bA + 4096 + row * 64 + sl * 8);
      }

    pa_t pa0[4], pa1[4];
#pragma unroll
    for (int qg = 0; qg < 4; ++qg) {
      f32x4 s[4];
#pragma unroll
      for (int tt = 0; tt < 4; ++tt) {
        f32x4 z = {0.f, 0.f, 0.f, 0.f};
        s[tt] = __builtin_amdgcn_mfma_f32_16x16x32_bf16(kf[tt * 2], aq[qg][0], z, 0, 0, 0);
        s[tt] = __builtin_amdgcn_mfma_f32_16x16x32_bf16(kf[tt * 2 + 1], aq[qg][1], s[tt], 0, 0, 0);
      }
      float acc_e = 0.f;
#pragma unroll
      for (int tt = 0; tt < 4; ++tt) {
        float e0 = __builtin_amdgcn_exp2f(s[tt][0]);
        float e1 = __builtin_amdgcn_exp2f(s[tt][1]);
        float e2 = __builtin_amdgcn_exp2f(s[tt][2]);
        float e3 = __builtin_amdgcn_exp2f(s[tt][3]);
        pa0[qg].u[tt] = pack_hi(e0, e1);
        pa1[qg].u[tt] = pack_hi(e2, e3);
        acc_e += (e0 + e1) + (e2 + e3);
      }
      lrow[qg] += acc_e;
    }

#pragma unroll
    for (int qg = 0; qg < 4; ++qg)
#pragma unroll
      for (int db = 0; db < 4; ++db) {
        y[qg][db] = __builtin_amdgcn_mfma_f32_16x16x32_bf16(pa0[qg].v, vf[db * 2], y[qg][db], 0, 0, 0);
        y[qg][db] = __builtin_amdgcn_mfma_f32_16x16x32_bf16(pa1[qg].v, vf[db * 2 + 1], y[qg][db], 0, 0, 0);
      }

    if (kv + 2 < T_SEQ / 64) STAGE(kv + 2, bC)

    unsigned short* tmp = bA; bA = bB; bB = bC; bC = tmp;
  }
#undef STAGE

  const int b = bh >> 4, h = bh & 15;
#pragma unroll
  for (int qg = 0; qg < 4; ++qg) {
    float sm = lrow[qg];
    sm += __shfl_xor(sm, 16);
    sm += __shfl_xor(sm, 32);
    float inv = 1.0f / sm;
#pragma unroll
    for (int r = 0; r < 4; ++r) {
      float iv = __shfl(inv, lg * 4 + r);
      int row = qbase + qg * 16 + lg * 4 + r;
#pragma unroll
      for (int db = 0; db < 4; ++db) {
        int d = db * 16 + lq;
        yw[((size_t)(b * T_SEQ + row)) * C_DIM + h * 64 + d] = f2bf(y[qg][db][r] * iv);
      }
    }
  }
}

// ---------------------------------------------------------------- launch
extern "C" void kernel_launch(void* const* d_in, const int* in_sizes, int n_in,
                              void* d_out, int out_size, void* d_ws, size_t ws_size,
                              hipStream_t stream) {
  (void)in_sizes; (void)n_in; (void)out_size; (void)ws_size;
  const float* x      = (const float*)d_in[0];
  const float* w_attn = (const float*)d_in[1];
  const float* w_proj = (const float*)d_in[2];
  float* out = (float*)d_out;

  unsigned short* ws = (unsigned short*)d_ws;
  const size_t XB = (size_t)M_ROWS * C_DIM;          // 8,388,608
  unsigned short* xb  = ws;                          // x bf16 [8192,1024]; reused as y after attn
  unsigned short* wab = xb + XB;                     // w_attn bf16 [3072,1024]
  unsigned short* wpb = wab + (size_t)3072 * 1024;   // w_proj bf16 [1024,1024]
  unsigned short* qws = wpb + (size_t)1024 * 1024;   // q [BH,T,D] (pre-scaled by 0.125*log2e)
  unsigned short* kws = qws + XB;                    // k [BH,T,D]
  unsigned short* vws = kws + XB;                    // v^T [BH,D,T'] k-permuted
  unsigned short* yws = xb;                          // attention output [B,T,C] (xb dead by then)

  cast_all_kernel<<<3145728 / 256, 256, 0, stream>>>(x, w_attn, w_proj, xb, wab, wpb);

  gemm_qkv_kernel<<<768, 512, 0, stream>>>(xb, wab, qws, kws, vws);
  attn_kernel<<<512, 256, 0, stream>>>(qws, kws, vws, yws);
  gemm_proj_kernel<<<512, 256, 0, stream>>>(yws, wpb, out);
}

// Round 8
// 177.469 us; speedup vs baseline: 1.4221x; 1.0257x over previous
//
#include <hip/hip_runtime.h>

// Problem constants
#define T_SEQ 2048
#define C_DIM 1024
#define H_NUM 16
#define H_D   64
#define B_NUM 4
#define M_ROWS 8192   // B*T

typedef __attribute__((ext_vector_type(4))) float f32x4;
typedef __attribute__((ext_vector_type(8))) short bf16x8;   // 8 bf16 = 4 VGPRs (per guide §3)

__device__ __forceinline__ unsigned short f2bf(float f) {
  union { float f; unsigned int u; } a;
  a.f = f;
  unsigned int u = a.u;
  u += 0x7fffu + ((u >> 16) & 1u);   // RNE
  return (unsigned short)(u >> 16);
}

__device__ __forceinline__ unsigned int fbits(float f) {
  union { float f; unsigned int u; } a; a.f = f; return a.u;
}

// pack the high halves (bf16-truncate) of two f32 into one u32: {hi(b), hi(a)}
__device__ __forceinline__ unsigned int pack_hi(float a, float b) {
#if __has_builtin(__builtin_amdgcn_perm)
  return __builtin_amdgcn_perm(fbits(b), fbits(a), 0x07060302u);  // 1 VALU op
#else
  return (fbits(b) & 0xffff0000u) | (fbits(a) >> 16);
#endif
}

// async global->LDS, 16B per lane; LDS dest = wave-uniform base + lane*16
__device__ __forceinline__ void gload_lds16(const unsigned short* g, unsigned short* l) {
  __builtin_amdgcn_global_load_lds(
      (const __attribute__((address_space(1))) unsigned int*)g,
      (__attribute__((address_space(3))) unsigned int*)l, 16, 0, 0);
}

// ---------------------------------------------------------------- fused cast fp32 -> bf16
__global__ __launch_bounds__(256) void cast_all_kernel(const float* __restrict__ x,
                                                       const float* __restrict__ wa,
                                                       const float* __restrict__ wp,
                                                       unsigned short* __restrict__ xb,
                                                       unsigned short* __restrict__ wab,
                                                       unsigned short* __restrict__ wpb) {
  int i = blockIdx.x * 256 + threadIdx.x;
  const float* src;
  unsigned short* dst;
  int off;
  if (i < 2097152) {           // x: 8192*1024/4
    src = x; dst = xb; off = i;
  } else if (i < 2883584) {    // w_attn: 3072*1024/4
    src = wa; dst = wab; off = i - 2097152;
  } else {                     // w_proj: 1024*1024/4
    src = wp; dst = wpb; off = i - 2883584;
  }
  float4 v = reinterpret_cast<const float4*>(src)[off];
  ushort4 o;
  o.x = f2bf(v.x); o.y = f2bf(v.y); o.z = f2bf(v.z); o.w = f2bf(v.w);
  reinterpret_cast<ushort4*>(dst)[off] = o;
}

// ---------------------------------------------------------------- GEMM  C = A * B^T
// Round 8: RECOMBINATION of measured-best components. Closed model from
// rounds 0/4/7: the 2-phase structure's staging rate is ~4.2-4.6 B/cy per
// RESIDENT BLOCK (TLP-bound, not structure-fixed), so TF = I x 4.4 x
// (blk/CU) x 0.614 -- verified on all three rounds. Under the constraints
// (acc <= 64 f32/thread at 4 blk/CU unified-register cap; BM=128 fixed by
// the 256-thread fragment geometry; grid must be an exact multiple of the
// 1024 resident slots), round-4's 128x96 EPI0 is the family optimum:
//   EPI0: BN=96, grid 64x32=2048 = exactly 2 rounds at 4 blk/CU (91.5 us).
// Round-7's totals isolated gemm1: BN=128 grid 512 beats BN=64 grid 1024
// by ~8-12 us ("others" 75.3 vs 87.4):
//   EPI1: BN=128, grid 64x8=512.
// Loop body / swizzle verbatim (0 bank conflicts all rounds): BK=64,
// single LDS buffer, pre-swizzled source + linear LDS dest + swizzled
// ds_read (slot ^ (row&7)); T1 bijective XCD swizzle (NWG % 8 == 0).
// EPI 0: QKV epilogue -> q*0.125*log2e, k [BH,T,D], v^T [BH,D,T'] k-permuted
// EPI 1: plain fp32 row-major [M,1024] output
template <int EPI>
__global__ __launch_bounds__(256, 4) void gemm_bt_kernel(
    const unsigned short* __restrict__ A,
    const unsigned short* __restrict__ Bw,
    unsigned short* __restrict__ q_ws,
    unsigned short* __restrict__ k_ws,
    unsigned short* __restrict__ v_ws,
    float* __restrict__ outf) {
  constexpr int BN  = (EPI == 0) ? 96 : 128;
  constexpr int NN  = (EPI == 0) ? 3072 : 1024;
  constexpr int NBC = NN / BN;           // 32 or 8
  constexpr int NFR = BN / 32;           // n-frags per wave: 3 or 4
  constexpr int BLD = BN * 8 / 256;      // B staging chunks per thread: 3 or 4
  constexpr int KK  = 1024;
  constexpr int KT  = KK / 64;           // 16
  constexpr int NWG = 64 * NBC;          // 2048 or 512 (both % 8 == 0)

  __shared__ unsigned short lds[8192 + BN * 64];   // A 16KB | B 12KB/16KB

  // T1: bijective XCD-aware swizzle (NWG % 8 == 0)
  const int bid = blockIdx.x;
  const int logical = (bid & 7) * (NWG / 8) + (bid >> 3);
  const int rb = logical / NBC, cb = logical % NBC;

  const int t = threadIdx.x;
  const int w = t >> 6, l = t & 63;
  const int wr = w >> 1, wc = w & 1;
  const int lq = l & 15, lg = l >> 4;

  const size_t a_base = (size_t)(rb * 128) * KK;
  const size_t b_base = (size_t)(cb * BN) * KK;

  // staging chunk c = t + 256*i -> (row=c>>3, slot=c&7), src slot ^= row&7
  int aRow[4], aGs[4];
#pragma unroll
  for (int i = 0; i < 4; ++i) {
    int c = t + 256 * i;
    aRow[i] = c >> 3;
    aGs[i] = (c & 7) ^ (aRow[i] & 7);
  }
  int bRow[BLD], bGs[BLD];
#pragma unroll
  for (int i = 0; i < BLD; ++i) {
    int c = t + 256 * i;
    bRow[i] = c >> 3;
    bGs[i] = (c & 7) ^ (bRow[i] & 7);
  }

  f32x4 acc[4][NFR] = {};

  for (int kt = 0; kt < KT; ++kt) {
    const int ko = kt * 64;
#pragma unroll
    for (int i = 0; i < 4; ++i)
      gload_lds16(A + a_base + (size_t)aRow[i] * KK + ko + aGs[i] * 8,
                  &lds[(t + 256 * i) * 8]);
#pragma unroll
    for (int i = 0; i < BLD; ++i)
      gload_lds16(Bw + b_base + (size_t)bRow[i] * KK + ko + bGs[i] * 8,
                  &lds[8192 + (t + 256 * i) * 8]);
    __syncthreads();   // drains vmcnt -> tile kt fully in LDS

#pragma unroll
    for (int kk = 0; kk < 2; ++kk) {
      const int sg = kk * 4 + lg;
      bf16x8 af[4], bfv[NFR];
#pragma unroll
      for (int i = 0; i < 4; ++i) {
        int R = wr * 64 + i * 16 + lq;
        af[i] = *reinterpret_cast<const bf16x8*>(&lds[(R * 8 + (sg ^ (R & 7))) * 8]);
      }
#pragma unroll
      for (int j = 0; j < NFR; ++j) {
        int R = wc * (BN / 2) + j * 16 + lq;
        bfv[j] = *reinterpret_cast<const bf16x8*>(&lds[8192 + (R * 8 + (sg ^ (R & 7))) * 8]);
      }
#pragma unroll
      for (int i = 0; i < 4; ++i)
#pragma unroll
        for (int j = 0; j < NFR; ++j)
          acc[i][j] = __builtin_amdgcn_mfma_f32_16x16x32_bf16(af[i], bfv[j], acc[i][j], 0, 0, 0);
    }
    __syncthreads();   // all reads of the buffer done before next stage (WAR)
  }

  // epilogue: C/D layout col = lane&15, row = (lane>>4)*4 + reg  (m89-verified)
#pragma unroll
  for (int i = 0; i < 4; ++i) {
#pragma unroll
    for (int j = 0; j < NFR; ++j) {
#pragma unroll
      for (int r = 0; r < 4; ++r) {
        int m = rb * 128 + wr * 64 + i * 16 + lg * 4 + r;
        int n = cb * BN + wc * (BN / 2) + j * 16 + lq;
        float v = acc[i][j][r];
        if (EPI == 0) {
          int which = n >> 10;
          int h = (n >> 6) & 15;
          int d = n & 63;
          int b = m >> 11;
          int tt = m & 2047;
          int bh = b * H_NUM + h;
          if (which == 0) {
            // fold softmax scale AND log2(e) so attention uses exp2 directly
            q_ws[((size_t)bh * T_SEQ + tt) * H_D + d] = f2bf(v * 0.18033688f);
          } else if (which == 1) {
            k_ws[((size_t)bh * T_SEQ + tt) * H_D + d] = f2bf(v);
          } else {
            // V transposed [BH,D,T'] with per-64-tile k-permutation matching
            // the swapped-QK^T in-register P layout (bijective bit shuffle)
            int k0 = tt & 63;
            int tp = (tt & ~63) | ((k0 & 12) << 1) | ((k0 & 48) >> 3) | (k0 & 1) | ((k0 & 2) << 4);
            v_ws[((size_t)bh * H_D + d) * T_SEQ + tp] = f2bf(v);
          }
        } else {
          outf[(size_t)m * 1024 + n] = v;
        }
      }
    }
  }
}

// ---------------------------------------------------------------- flash attention
// (unchanged -- counted-vmcnt 3-buffer pipeline, swapped QK^T in-lane softmax)
__global__ __launch_bounds__(256, 2) void attn_kernel(
    const unsigned short* __restrict__ qw,
    const unsigned short* __restrict__ kw,
    const unsigned short* __restrict__ vtw,
    unsigned short* __restrict__ yw) {
  __shared__ unsigned short kv_lds[3][8192];   // 3 bufs x (K 4096 | V 4096 shorts) = 48KB

  const int bid = blockIdx.x;
  const int bh = (bid & 7) * 8 + ((bid >> 3) & 7);
  const int qblk = bid >> 6;                    // 0..7, 256 rows each

  const int t = threadIdx.x;
  const int w = t >> 6, l = t & 63;
  const int lq = l & 15, lg = l >> 4;
  const int qbase = qblk * 256 + w * 64;
  const size_t head_off = (size_t)bh * T_SEQ * H_D;

  bf16x8 aq[4][2];
#pragma unroll
  for (int qg = 0; qg < 4; ++qg)
#pragma unroll
    for (int kk = 0; kk < 2; ++kk)
      aq[qg][kk] = *reinterpret_cast<const bf16x8*>(
          qw + head_off + (size_t)(qbase + qg * 16 + lq) * H_D + kk * 32 + lg * 8);

  const unsigned short* sbase[4];
  int sstep[4];
#pragma unroll
  for (int i = 0; i < 4; ++i) {
    int c = w * 64 + l + 256 * i;
    if (c < 512) {
      int row = c >> 3, sl = (c & 7) ^ (row & 7);
      sbase[i] = kw + head_off + row * H_D + sl * 8;
      sstep[i] = 64 * H_D;
    } else {
      int c2 = c - 512;
      int row = c2 >> 3, sl = (c2 & 7) ^ (row & 7);
      sbase[i] = vtw + head_off + (size_t)row * T_SEQ + sl * 8;
      sstep[i] = 64;
    }
  }

  unsigned short* bA = &kv_lds[0][0];
  unsigned short* bB = &kv_lds[1][0];
  unsigned short* bC = &kv_lds[2][0];

#define STAGE(KV, DST)                                                              \
  { _Pragma("unroll")                                                               \
    for (int i = 0; i < 4; ++i)                                                     \
      gload_lds16(sbase[i] + (size_t)(KV) * sstep[i], (DST) + (w * 64 + 256 * i) * 8); }

  STAGE(0, bA)
  STAGE(1, bB)

  f32x4 y[4][4] = {};
  float lrow[4] = {0.f, 0.f, 0.f, 0.f};
  union pa_t { bf16x8 v; unsigned int u[4]; };

  for (int kv = 0; kv < T_SEQ / 64; ++kv) {
    if (kv == T_SEQ / 64 - 1) {
      asm volatile("s_waitcnt vmcnt(0)" ::: "memory");
    } else {
      asm volatile("s_waitcnt vmcnt(4)" ::: "memory");
    }
    __builtin_amdgcn_s_barrier();

    bf16x8 kf[8], vf[8];
#pragma unroll
    for (int f = 0; f < 8; ++f) {
      int row = (f >> 1) * 16 + lq;
      int sl = ((f & 1) * 4 + lg) ^ (lq & 7);
      kf[f] = *reinterpret_cast<const bf16x8*>(bA + row * 64 + sl * 8);
    }
#pragma unroll
    for (int db = 0; db < 4; ++db)
#pragma unroll
      for (int ks = 0; ks < 2; ++ks) {
        int row = db * 16 + lq;
        int sl = (ks * 4 + lg) ^ (lq & 7);
        vf[db * 2 + ks] = *reinterpret_cast<const bf16x8*>(bA + 4096 + row * 64 + sl * 8);
      }

    pa_t pa0[4], pa1[4];
#pragma unroll
    for (int qg = 0; qg < 4; ++qg) {
      f32x4 s[4];
#pragma unroll
      for (int tt = 0; tt < 4; ++tt) {
        f32x4 z = {0.f, 0.f, 0.f, 0.f};
        s[tt] = __builtin_amdgcn_mfma_f32_16x16x32_bf16(kf[tt * 2], aq[qg][0], z, 0, 0, 0);
        s[tt] = __builtin_amdgcn_mfma_f32_16x16x32_bf16(kf[tt * 2 + 1], aq[qg][1], s[tt], 0, 0, 0);
      }
      float acc_e = 0.f;
#pragma unroll
      for (int tt = 0; tt < 4; ++tt) {
        float e0 = __builtin_amdgcn_exp2f(s[tt][0]);
        float e1 = __builtin_amdgcn_exp2f(s[tt][1]);
        float e2 = __builtin_amdgcn_exp2f(s[tt][2]);
        float e3 = __builtin_amdgcn_exp2f(s[tt][3]);
        pa0[qg].u[tt] = pack_hi(e0, e1);
        pa1[qg].u[tt] = pack_hi(e2, e3);
        acc_e += (e0 + e1) + (e2 + e3);
      }
      lrow[qg] += acc_e;
    }

#pragma unroll
    for (int qg = 0; qg < 4; ++qg)
#pragma unroll
      for (int db = 0; db < 4; ++db) {
        y[qg][db] = __builtin_amdgcn_mfma_f32_16x16x32_bf16(pa0[qg].v, vf[db * 2], y[qg][db], 0, 0, 0);
        y[qg][db] = __builtin_amdgcn_mfma_f32_16x16x32_bf16(pa1[qg].v, vf[db * 2 + 1], y[qg][db], 0, 0, 0);
      }

    if (kv + 2 < T_SEQ / 64) STAGE(kv + 2, bC)

    unsigned short* tmp = bA; bA = bB; bB = bC; bC = tmp;
  }
#undef STAGE

  const int b = bh >> 4, h = bh & 15;
#pragma unroll
  for (int qg = 0; qg < 4; ++qg) {
    float sm = lrow[qg];
    sm += __shfl_xor(sm, 16);
    sm += __shfl_xor(sm, 32);
    float inv = 1.0f / sm;
#pragma unroll
    for (int r = 0; r < 4; ++r) {
      float iv = __shfl(inv, lg * 4 + r);
      int row = qbase + qg * 16 + lg * 4 + r;
#pragma unroll
      for (int db = 0; db < 4; ++db) {
        int d = db * 16 + lq;
        yw[((size_t)(b * T_SEQ + row)) * C_DIM + h * 64 + d] = f2bf(y[qg][db][r] * iv);
      }
    }
  }
}

// ---------------------------------------------------------------- launch
extern "C" void kernel_launch(void* const* d_in, const int* in_sizes, int n_in,
                              void* d_out, int out_size, void* d_ws, size_t ws_size,
                              hipStream_t stream) {
  (void)in_sizes; (void)n_in; (void)out_size; (void)ws_size;
  const float* x      = (const float*)d_in[0];
  const float* w_attn = (const float*)d_in[1];
  const float* w_proj = (const float*)d_in[2];
  float* out = (float*)d_out;

  unsigned short* ws = (unsigned short*)d_ws;
  const size_t XB = (size_t)M_ROWS * C_DIM;          // 8,388,608
  unsigned short* xb  = ws;                          // x bf16 [8192,1024]; reused as y after attn
  unsigned short* wab = xb + XB;                     // w_attn bf16 [3072,1024]
  unsigned short* wpb = wab + (size_t)3072 * 1024;   // w_proj bf16 [1024,1024]
  unsigned short* qws = wpb + (size_t)1024 * 1024;   // q [BH,T,D] (pre-scaled by 0.125*log2e)
  unsigned short* kws = qws + XB;                    // k [BH,T,D]
  unsigned short* vws = kws + XB;                    // v^T [BH,D,T'] k-permuted
  unsigned short* yws = xb;                          // attention output [B,T,C] (xb dead by then)

  cast_all_kernel<<<3145728 / 256, 256, 0, stream>>>(x, w_attn, w_proj, xb, wab, wpb);

  gemm_bt_kernel<0><<<2048, 256, 0, stream>>>(xb, wab, qws, kws, vws, nullptr);
  attn_kernel<<<512, 256, 0, stream>>>(qws, kws, vws, yws);
  gemm_bt_kernel<1><<<512, 256, 0, stream>>>(yws, wpb, nullptr, nullptr, nullptr, out);
}